// Round 1
// baseline (553.894 us; speedup 1.0000x reference)
//
#include <hip/hip_runtime.h>
#include <stdint.h>
#include <stddef.h>

// HybridDiffusion: z_t = argmax_v probs[v] / (1e-10 - log(noise[v] + 1e-10))
// probs has only 3 distinct values per (b,s): mask-col, hit-col, uniform.
// Memory-bound: must stream 411.7 MB of noise. One block per row.

static constexpr int VOCAB   = 50257;
static constexpr int MASK_ID = 50256;
// LOG_B = clip(-log1p((1-P)/P * VOCAB/2), -20, None) == -20.0 exactly
// (unclipped value is ~-30.13), so B_EXP = exp(-20.0).
static constexpr double B_EXP_D = 2.061153622438558e-09;

__global__ __launch_bounds__(256) void hd_argmax_kernel(
    const int*   __restrict__ ids,    // (4,512) flat
    const float* __restrict__ tv,     // (4,)
    const float* __restrict__ noise,  // (4,512,50257) flat
    int*         __restrict__ out)    // (4,512) flat int32
{
    const int row = blockIdx.x;       // 0..2047
    const int tid = threadIdx.x;
    const int b   = row >> 9;         // row / 512

    // Per-batch coefficients, f32 op-for-op as the reference (GAMMA=1 -> pow folds)
    const float t   = tv[b];
    const float tg  = t;
    const float t1g = 1.0f - t;
    const float c   = sqrtf(tg) * sqrtf(t1g) * (float)B_EXP_D;
    float Cd = tg + t1g + 50255.0f * c;          // (VOCAB-2)*c
    Cd = fmaxf(Cd, 1e-4f);                        // clip(_, EPS, None)
    const float pc = c / Cd;                      // cC
    const float ph = (t1g - c) / Cd + c / Cd;     // alpha + cC (kept as two divs + add)
    const float pm = tg / Cd;                     // mC
    const int   x  = ids[row];

    const float* __restrict__ rowp = noise + (size_t)row * (size_t)VOCAB;

    // Rows drift alignment: (row*50257) % 4 == row % 4. Scalar head to 16B align.
    const int k     = (4 - (row & 3)) & 3;
    const int nvec  = (VOCAB - k) >> 2;
    const int tail0 = k + (nvec << 2);

    float best = -1.0f;   // all ratios >= 0
    int   bidx = 0;

    auto consider = [&](float u, int idx) {
        const float g = 1e-10f - logf(u + 1e-10f);           // > 0 always
        const float p = (idx == MASK_ID) ? pm : ((idx == x) ? ph : pc);
        const float r = p / g;
        if (r > best) { best = r; bidx = idx; }              // strict > keeps first max
    };

    // head (0..3 scalars)
    if (tid < k) consider(rowp[tid], tid);

    // aligned float4 body
    const float4* __restrict__ vp = reinterpret_cast<const float4*>(rowp + k);
    for (int i = tid; i < nvec; i += 256) {
        const float4 v = vp[i];
        const int base = k + (i << 2);
        consider(v.x, base);
        consider(v.y, base + 1);
        consider(v.z, base + 2);
        consider(v.w, base + 3);
    }

    // tail (0..3 scalars)
    if (tid < VOCAB - tail0) consider(rowp[tail0 + tid], tail0 + tid);

    // Wave (64-lane) reduction: max val, min idx on ties (first-occurrence argmax).
    #pragma unroll
    for (int off = 32; off > 0; off >>= 1) {
        const float ov = __shfl_down(best, off, 64);
        const int   oi = __shfl_down(bidx, off, 64);
        if (ov > best || (ov == best && oi < bidx)) { best = ov; bidx = oi; }
    }

    __shared__ float sv[4];
    __shared__ int   si[4];
    const int wid = tid >> 6;
    if ((tid & 63) == 0) { sv[wid] = best; si[wid] = bidx; }
    __syncthreads();
    if (tid == 0) {
        #pragma unroll
        for (int w = 1; w < 4; ++w) {
            if (sv[w] > best || (sv[w] == best && si[w] < bidx)) { best = sv[w]; bidx = si[w]; }
        }
        out[row] = bidx;
    }
}

extern "C" void kernel_launch(void* const* d_in, const int* in_sizes, int n_in,
                              void* d_out, int out_size, void* d_ws, size_t ws_size,
                              hipStream_t stream) {
    const int*   ids   = (const int*)  d_in[0];  // input_ids (4,512) int32
    const float* t     = (const float*)d_in[1];  // t (4,) f32
    const float* noise = (const float*)d_in[2];  // noise (4,512,50257) f32
    int* out = (int*)d_out;                      // argmax indices, int32

    hd_argmax_kernel<<<dim3(2048), dim3(256), 0, stream>>>(ids, t, noise, out);
}

// Round 2
// 536.155 us; speedup vs baseline: 1.0331x; 1.0331x over previous
//
#include <hip/hip_runtime.h>
#include <stdint.h>
#include <stddef.h>

// HybridDiffusion: z_t = argmax_v p[v] / (1e-10 - log(noise[v] + 1e-10))
// p has only 3 distinct values per row (mask col, hit col, uniform).
// g(u) is strictly decreasing in u, so within a class argmax(p/g) == argmax(u).
// => scan is a pure noise-max (memory-bound); exact f32 reference formula is
// applied only to the 3 class winners at the end (first-index tie-break).

static constexpr int VOCAB   = 50257;
static constexpr int MASK_ID = 50256;
static constexpr int NSCAN   = VOCAB - 1;   // [0, 50256): excludes mask col structurally
// LOG_B = clip(-log1p((1-P)/P * VOCAB/2), -20, None) == -20.0 exactly -> B_EXP = exp(-20)
static constexpr double B_EXP_D = 2.061153622438558e-09;

__global__ __launch_bounds__(256) void hd_argmax_kernel(
    const int*   __restrict__ ids,    // (4,512)
    const float* __restrict__ tv,     // (4,)
    const float* __restrict__ noise,  // (4,512,50257)
    int*         __restrict__ out)    // (4,512) int32
{
    const int row = blockIdx.x;       // 0..2047
    const int tid = threadIdx.x;
    const int x   = ids[row];         // hit column (may equal MASK_ID)

    const float* __restrict__ rowp = noise + (size_t)row * (size_t)VOCAB;

    // rowp is 4B-aligned; (row*50257 + k) % 4 == 0 when k == (-row) mod 4.
    const int k    = (4 - (row & 3)) & 3;
    const int nvec = (NSCAN - k) >> 2;
    const int tail0 = k + (nvec << 2);

    // Running max of raw noise over uniform columns (strict > keeps first index
    // within a thread's increasing visit order).
    float bu   = -1.0f;
    int   bidx = 0;

    auto consider = [&](float u, int idx) {
        if (u > bu && idx != x) { bu = u; bidx = idx; }
    };

    if (tid < k) consider(rowp[tid], tid);

    const float4* __restrict__ vp = reinterpret_cast<const float4*>(rowp + k);
    for (int i = tid; i < nvec; i += 256) {
        const float4 v = vp[i];
        const int base = k + (i << 2);
        consider(v.x, base);
        consider(v.y, base + 1);
        consider(v.z, base + 2);
        consider(v.w, base + 3);
    }

    if (tid < NSCAN - tail0) consider(rowp[tail0 + tid], tail0 + tid);

    // Wave reduction: max u, min idx on exact ties.
    #pragma unroll
    for (int off = 32; off > 0; off >>= 1) {
        const float ov = __shfl_down(bu, off, 64);
        const int   oi = __shfl_down(bidx, off, 64);
        if (ov > bu || (ov == bu && oi < bidx)) { bu = ov; bidx = oi; }
    }

    __shared__ float sv[4];
    __shared__ int   si[4];
    const int wid = tid >> 6;
    if ((tid & 63) == 0) { sv[wid] = bu; si[wid] = bidx; }
    __syncthreads();

    if (tid == 0) {
        #pragma unroll
        for (int w = 1; w < 4; ++w) {
            if (sv[w] > bu || (sv[w] == bu && si[w] < bidx)) { bu = sv[w]; bidx = si[w]; }
        }

        // Coefficients, f32 op-for-op as the reference (GAMMA=1 -> pow folds).
        const float t   = tv[row >> 9];
        const float tg  = t;
        const float t1g = 1.0f - t;
        const float c   = sqrtf(tg) * sqrtf(t1g) * (float)B_EXP_D;
        float Cd = tg + t1g + 50255.0f * c;
        Cd = fmaxf(Cd, 1e-4f);
        const float pc = c / Cd;                      // uniform prob
        const float ph = (t1g - c) / Cd + c / Cd;     // alpha + cC
        const float pm = tg / Cd;                     // mask prob

        // Exact reference ratio for the 3 class winners; first-index tie-break.
        float best_r = pc / (1e-10f - logf(bu + 1e-10f));
        int   best_i = bidx;

        if (x != MASK_ID) {
            const float uh = rowp[x];
            const float rh = ph / (1e-10f - logf(uh + 1e-10f));
            if (rh > best_r || (rh == best_r && x < best_i)) { best_r = rh; best_i = x; }
        }
        {
            const float um = rowp[MASK_ID];
            const float rm = pm / (1e-10f - logf(um + 1e-10f));
            if (rm > best_r) { best_i = MASK_ID; }    // mask has the largest index
        }
        out[row] = best_i;
    }
}

extern "C" void kernel_launch(void* const* d_in, const int* in_sizes, int n_in,
                              void* d_out, int out_size, void* d_ws, size_t ws_size,
                              hipStream_t stream) {
    const int*   ids   = (const int*)  d_in[0];
    const float* t     = (const float*)d_in[1];
    const float* noise = (const float*)d_in[2];
    int* out = (int*)d_out;

    hd_argmax_kernel<<<dim3(2048), dim3(256), 0, stream>>>(ids, t, noise, out);
}

// Round 4
// 503.364 us; speedup vs baseline: 1.1004x; 1.0651x over previous
//
#include <hip/hip_runtime.h>
#include <stdint.h>
#include <stddef.h>

// HybridDiffusion: z_t = argmax_v p[v] / (1e-10 - log(noise[v] + 1e-10))
// g(u) strictly decreasing => within a prob-class, argmax(p/g) == argmax(u).
// Scan = pure noise-max over [0,50256) excluding the hit column; exact f32
// reference ratio applied to the 3 class winners at the end.
// This round: 4x unrolled independent loads (MLP) + dual max chains (ILP)
// + nontemporal loads (read-once stream).

static constexpr int VOCAB   = 50257;
static constexpr int MASK_ID = 50256;
static constexpr int NSCAN   = VOCAB - 1;   // mask col excluded structurally
static constexpr double B_EXP_D = 2.061153622438558e-09;  // exp(-20)

typedef float f32x4 __attribute__((ext_vector_type(4)));

__global__ __launch_bounds__(256) void hd_argmax_kernel(
    const int*   __restrict__ ids,    // (4,512)
    const float* __restrict__ tv,     // (4,)
    const float* __restrict__ noise,  // (4,512,50257)
    int*         __restrict__ out)    // (4,512) int32
{
    const int row = blockIdx.x;       // 0..2047
    const int tid = threadIdx.x;
    const int x   = ids[row];         // hit column (may equal MASK_ID)

    const float* __restrict__ rowp = noise + (size_t)row * (size_t)VOCAB;

    // Align body to 16B: (row*50257 + k) % 4 == 0 for k == (-row) mod 4.
    const int k     = (4 - (row & 3)) & 3;
    const int nvec  = (NSCAN - k) >> 2;
    const int tail0 = k + (nvec << 2);

    // Two independent (max, first-idx) chains; each visits increasing indices.
    float bu0 = -1.0f, bu1 = -1.0f;
    int   bi0 = 0,     bi1 = 0;

    auto c0 = [&](float u, int idx) { if (u > bu0 && idx != x) { bu0 = u; bi0 = idx; } };
    auto c1 = [&](float u, int idx) { if (u > bu1 && idx != x) { bu1 = u; bi1 = idx; } };

    if (tid < k) c0(rowp[tid], tid);

    const f32x4* __restrict__ vp = reinterpret_cast<const f32x4*>(rowp + k);

    int i = tid;
    // Main loop: 4 independent dwordx4 loads in flight per wave.
    for (; i + 768 < nvec; i += 1024) {
        const f32x4 v0 = __builtin_nontemporal_load(vp + i);
        const f32x4 v1 = __builtin_nontemporal_load(vp + i + 256);
        const f32x4 v2 = __builtin_nontemporal_load(vp + i + 512);
        const f32x4 v3 = __builtin_nontemporal_load(vp + i + 768);
        const int b0 = k + (i << 2);
        c0(v0.x, b0);        c0(v0.y, b0 + 1);    c0(v0.z, b0 + 2);    c0(v0.w, b0 + 3);
        c0(v1.x, b0 + 1024); c0(v1.y, b0 + 1025); c0(v1.z, b0 + 1026); c0(v1.w, b0 + 1027);
        c1(v2.x, b0 + 2048); c1(v2.y, b0 + 2049); c1(v2.z, b0 + 2050); c1(v2.w, b0 + 2051);
        c1(v3.x, b0 + 3072); c1(v3.y, b0 + 3073); c1(v3.z, b0 + 3074); c1(v3.w, b0 + 3075);
    }
    // Cleanup vec loop.
    for (; i < nvec; i += 256) {
        const f32x4 v = __builtin_nontemporal_load(vp + i);
        const int b = k + (i << 2);
        c0(v.x, b); c0(v.y, b + 1); c0(v.z, b + 2); c0(v.w, b + 3);
    }
    // Scalar tail (0..3 elements).
    if (tid < NSCAN - tail0) c0(rowp[tail0 + tid], tail0 + tid);

    // Merge chains: max val, min idx on exact tie -> first occurrence.
    float bu = bu0; int bidx = bi0;
    if (bu1 > bu || (bu1 == bu && bi1 < bidx)) { bu = bu1; bidx = bi1; }

    // Wave (64-lane) reduction.
    #pragma unroll
    for (int off = 32; off > 0; off >>= 1) {
        const float ov = __shfl_down(bu, off, 64);
        const int   oi = __shfl_down(bidx, off, 64);
        if (ov > bu || (ov == bu && oi < bidx)) { bu = ov; bidx = oi; }
    }

    __shared__ float sv[4];
    __shared__ int   si[4];
    const int wid = tid >> 6;
    if ((tid & 63) == 0) { sv[wid] = bu; si[wid] = bidx; }
    __syncthreads();

    if (tid == 0) {
        #pragma unroll
        for (int w = 1; w < 4; ++w) {
            if (sv[w] > bu || (sv[w] == bu && si[w] < bidx)) { bu = sv[w]; bidx = si[w]; }
        }

        // Coefficients, f32 op-for-op as the reference (GAMMA=1 -> pow folds).
        const float t   = tv[row >> 9];
        const float tg  = t;
        const float t1g = 1.0f - t;
        const float c   = sqrtf(tg) * sqrtf(t1g) * (float)B_EXP_D;
        float Cd = tg + t1g + 50255.0f * c;
        Cd = fmaxf(Cd, 1e-4f);
        const float pc = c / Cd;                      // uniform prob
        const float ph = (t1g - c) / Cd + c / Cd;     // alpha + cC
        const float pm = tg / Cd;                     // mask prob

        float best_r = pc / (1e-10f - logf(bu + 1e-10f));
        int   best_i = bidx;

        if (x != MASK_ID) {
            const float uh = rowp[x];
            const float rh = ph / (1e-10f - logf(uh + 1e-10f));
            if (rh > best_r || (rh == best_r && x < best_i)) { best_r = rh; best_i = x; }
        }
        {
            const float um = rowp[MASK_ID];
            const float rm = pm / (1e-10f - logf(um + 1e-10f));
            if (rm > best_r) { best_i = MASK_ID; }    // mask is the largest index
        }
        out[row] = best_i;
    }
}

extern "C" void kernel_launch(void* const* d_in, const int* in_sizes, int n_in,
                              void* d_out, int out_size, void* d_ws, size_t ws_size,
                              hipStream_t stream) {
    const int*   ids   = (const int*)  d_in[0];
    const float* t     = (const float*)d_in[1];
    const float* noise = (const float*)d_in[2];
    int* out = (int*)d_out;

    hd_argmax_kernel<<<dim3(2048), dim3(256), 0, stream>>>(ids, t, noise, out);
}